// Round 6
// baseline (544.756 us; speedup 1.0000x reference)
//
#include <hip/hip_runtime.h>
#include <hip/hip_bf16.h>

// MoE layer, routed top-2 implementation.
// N=4096 tokens, D=768, F=3072, E=8. All inputs fp32; compute in f16 MFMA
// (fp32 accumulate), gating in fp64 for exact top-2 selection.

#define N_TOK 4096
#define DIM   768
#define FDIM  3072
#define NEXP  8

typedef __attribute__((ext_vector_type(8))) _Float16 f16x8;
typedef __attribute__((ext_vector_type(4))) _Float16 f16x4;
typedef __attribute__((ext_vector_type(4))) float     f32x4;

__device__ __forceinline__ float gelu_exact(float v) {
    return 0.5f * v * (1.0f + erff(v * 0.7071067811865475f));
}

// async global->LDS, 16B per lane. Dest must be wave-uniform base + lane*16.
__device__ __forceinline__ void gload_lds16(const _Float16* g, _Float16* l) {
    __builtin_amdgcn_global_load_lds(
        (const __attribute__((address_space(1))) void*)g,
        (__attribute__((address_space(3))) void*)l,
        16, 0, 0);
}

#define WAITV(N) asm volatile("s_waitcnt vmcnt(" #N ")" ::: "memory")
#define BAR()    __builtin_amdgcn_s_barrier()

// ---------------- cast x (fp32 -> f16), vectorized ----------------
__global__ __launch_bounds__(256) void cast_x_kernel(const float* __restrict__ x,
                                                     _Float16* __restrict__ xh) {
    int i = blockIdx.x * 256 + threadIdx.x;   // one float4 per thread, grid sized exactly
    float4 v = ((const float4*)x)[i];
    f16x4 o;
    o[0] = (_Float16)v.x; o[1] = (_Float16)v.y;
    o[2] = (_Float16)v.z; o[3] = (_Float16)v.w;
    ((f16x4*)xh)[i] = o;
}

// ---------------- merged transpose + cast for w1 and w2 ----------------
// fp32 [E][R][C] -> f16 [E][C][R]; blockIdx.y: 0..7 = w1 experts, 8..15 = w2.
__global__ __launch_bounds__(256) void transpose_cast2_kernel(const float* __restrict__ w1,
                                                              const float* __restrict__ w2,
                                                              _Float16* __restrict__ w1t,
                                                              _Float16* __restrict__ w2t) {
    const int z     = blockIdx.y;
    const int which = z >> 3;
    const int e     = z & 7;
    const float* in; _Float16* out; int R, C, tx, ty;
    if (which == 0) { in = w1; out = w1t; R = DIM;  C = FDIM; tx = blockIdx.x % (FDIM / 64); ty = blockIdx.x / (FDIM / 64); }
    else            { in = w2; out = w2t; R = FDIM; C = DIM;  tx = blockIdx.x % (DIM  / 64); ty = blockIdx.x / (DIM  / 64); }
    const size_t eoff = (size_t)e * R * C;
    const int c0 = tx * 64;
    const int r0 = ty * 64;
    __shared__ _Float16 tile[64][66];   // pitch 66 to soften bank conflicts
    const int t = threadIdx.x;
    #pragma unroll
    for (int it = 0; it < 4; it++) {
        int lin = it * 256 + t;
        int r  = lin >> 4;       // 0..63
        int c4 = lin & 15;       // float4 column group
        float4 v = *(const float4*)&in[eoff + (size_t)(r0 + r) * C + c0 + c4 * 4];
        tile[r][c4 * 4 + 0] = (_Float16)v.x;
        tile[r][c4 * 4 + 1] = (_Float16)v.y;
        tile[r][c4 * 4 + 2] = (_Float16)v.z;
        tile[r][c4 * 4 + 3] = (_Float16)v.w;
    }
    __syncthreads();
    #pragma unroll
    for (int it = 0; it < 4; it++) {
        int lin = it * 256 + t;
        int c  = lin >> 4;       // out row (= original column)
        int r4 = lin & 15;       // group of 4 original rows
        f16x4 o;
        #pragma unroll
        for (int j = 0; j < 4; j++) o[j] = tile[r4 * 4 + j][c];
        *(f16x4*)&out[eoff + (size_t)(c0 + c) * R + r0 + r4 * 4] = o;
    }
}

// ---------------- gating: fp64 logits, softmax, top-2, per-expert lists ----------------
__global__ __launch_bounds__(256) void gate_kernel(const float* __restrict__ x,
                                                   const float* __restrict__ gw,
                                                   const float* __restrict__ gb,
                                                   int* __restrict__ tok_list,
                                                   float* __restrict__ wt_list,
                                                   int* __restrict__ count) {
    const int gtid = blockIdx.x * 256 + threadIdx.x;
    const int n    = gtid >> 6;        // one wave per token
    const int lane = threadIdx.x & 63;
    if (n >= N_TOK) return;
    double part[NEXP];
    #pragma unroll
    for (int e = 0; e < NEXP; e++) part[e] = 0.0;
    for (int d = lane; d < DIM; d += 64) {
        float xv = x[n * DIM + d];
        const float* g = &gw[d * NEXP];
        #pragma unroll
        for (int e = 0; e < NEXP; e++) part[e] += (double)xv * (double)g[e];
    }
    #pragma unroll
    for (int e = 0; e < NEXP; e++) {
        double v = part[e];
        #pragma unroll
        for (int off = 32; off > 0; off >>= 1) v += __shfl_xor(v, off);
        part[e] = v + (double)gb[e];
    }
    if (lane == 0) {
        double mx = part[0];
        #pragma unroll
        for (int e = 1; e < NEXP; e++) mx = fmax(mx, part[e]);
        double ex[NEXP]; double s = 0.0;
        #pragma unroll
        for (int e = 0; e < NEXP; e++) { ex[e] = exp(part[e] - mx); s += ex[e]; }
        int i0 = 0;
        #pragma unroll
        for (int e = 1; e < NEXP; e++) if (ex[e] > ex[i0]) i0 = e;   // first-max tie-break, matches top_k
        int i1 = (i0 == 0) ? 1 : 0;
        #pragma unroll
        for (int e = 0; e < NEXP; e++) if (e != i0 && ex[e] > ex[i1]) i1 = e;
        float g0 = (float)(ex[i0] / s), g1 = (float)(ex[i1] / s);
        float dn = g0 + g1 + 1e-9f;
        float w0 = g0 / dn, w1 = g1 / dn;
        int s0 = atomicAdd(&count[i0], 1);
        tok_list[i0 * N_TOK + s0] = n;  wt_list[i0 * N_TOK + s0] = w0;
        int s1 = atomicAdd(&count[i1], 1);
        tok_list[i1 * N_TOK + s1] = n;  wt_list[i1 * N_TOK + s1] = w1;
    }
}

// ---------------- tiny prefix scan over 8 expert counts ----------------
__global__ void scan_kernel(const int* __restrict__ count, int* __restrict__ basep) {
    if (threadIdx.x == 0) {
        int s = 0;
        for (int e = 0; e < NEXP; e++) { basep[e] = s; s += count[e]; }
    }
}

// ---------------- GEMM1: h = gelu(x_gathered @ w1[e] + b1[e]) ----------------
// 128x128 tile, BK=32, 4 waves (2x2). 3-buffer counted-vmcnt pipeline (T3+T4),
// statically unrolled x3: per phase STAGE(t+2) -> vmcnt(8) -> s_barrier ->
// ds_read+MFMA -> s_barrier. Each tile's loads have ~2 compute phases to land,
// so the per-step HBM-latency drain of the __syncthreads loop disappears.
// Per-wave vmcnt ledger: 4 loads/tile; steady outstanding after issue = 12,
// wait(8) completes exactly the current tile; peel waits 8/4/0.
// LDS chunk XOR-swizzle ((row>>1)&3, both-sides) keeps ds_read 2-way-free.
// MFMA operands SWAPPED (mfma(bf,af)): D col=lane&15 -> token, row-reg ->
// 4 consecutive h columns -> vectorized f16x4 epilogue stores.
__global__ __launch_bounds__(256) void mm1_kernel(const _Float16* __restrict__ xh,
                                                  const _Float16* __restrict__ w1t,
                                                  const float* __restrict__ bias1,
                                                  const int* __restrict__ tok_list,
                                                  const int* __restrict__ count,
                                                  const int* __restrict__ basep,
                                                  _Float16* __restrict__ h) {
    const int e    = blockIdx.y;
    const int cnt  = count[e];
    const int row0 = blockIdx.z * 128;
    if (row0 >= cnt) return;
    const int col0 = blockIdx.x * 128;
    const int t    = threadIdx.x;
    const int lane = t & 63;
    const int wv   = t >> 6;
    const int wy   = wv >> 1, wx = wv & 1;
    const int m_lane = lane & 15, quad = lane >> 4;

    __shared__ __align__(16) _Float16 A0[128][32], A1[128][32], A2[128][32];
    __shared__ __align__(16) _Float16 B0[128][32], B1[128][32], B2[128][32];

    const int srow    = t >> 2;                         // 0..63 staging row
    const int kin     = (t & 3) * 8;                    // linear LDS dest chunk
    const int kin_src = ((t & 3) ^ ((srow >> 1) & 3)) * 8;   // inv-swizzled global chunk

    int i0 = row0 + srow;      if (i0 > cnt - 1) i0 = cnt - 1;
    int i1 = row0 + 64 + srow; if (i1 > cnt - 1) i1 = cnt - 1;
    const _Float16* pa0 = xh + (size_t)tok_list[e * N_TOK + i0] * DIM + kin_src;
    const _Float16* pa1 = xh + (size_t)tok_list[e * N_TOK + i1] * DIM + kin_src;
    const _Float16* pb0 = w1t + (size_t)e * FDIM * DIM + (size_t)(col0 + srow) * DIM + kin_src;
    const _Float16* pb1 = pb0 + (size_t)64 * DIM;

    f32x4 acc[4][4];
    #pragma unroll
    for (int i = 0; i < 4; i++)
        #pragma unroll
        for (int j = 0; j < 4; j++)
            acc[i][j] = (f32x4){0.f, 0.f, 0.f, 0.f};

    const int rc8 = (quad ^ ((m_lane >> 1) & 3)) * 8;   // swizzled read column

#define MM1_STAGE(Ad, Bd, kt) do { const int kk_ = (kt) * 32;          \
    gload_lds16(pa0 + kk_, &Ad[srow][kin]);                             \
    gload_lds16(pa1 + kk_, &Ad[64 + srow][kin]);                        \
    gload_lds16(pb0 + kk_, &Bd[srow][kin]);                             \
    gload_lds16(pb1 + kk_, &Bd[64 + srow][kin]); } while (0)

#define MM1_COMP(Ac, Bc) do { f16x8 af_[4], bf_[4];                                         \
    _Pragma("unroll") for (int i_ = 0; i_ < 4; i_++)                                        \
        af_[i_] = *(const f16x8*)&Ac[wy * 64 + i_ * 16 + m_lane][rc8];                      \
    _Pragma("unroll") for (int j_ = 0; j_ < 4; j_++)                                        \
        bf_[j_] = *(const f16x8*)&Bc[wx * 64 + j_ * 16 + m_lane][rc8];                      \
    _Pragma("unroll") for (int i_ = 0; i_ < 4; i_++)                                        \
        _Pragma("unroll") for (int j_ = 0; j_ < 4; j_++)                                    \
            acc[i_][j_] = __builtin_amdgcn_mfma_f32_16x16x32_f16(bf_[j_], af_[i_], acc[i_][j_], 0, 0, 0); } while (0)

    WAITV(0);                     // clean ledger (addr-setup loads drained)
    MM1_STAGE(A0, B0, 0);
    MM1_STAGE(A1, B1, 1);
    // main: 7 iters, tiles 0..20, stages through tile 22
    for (int tt = 0; tt < 21; tt += 3) {
        MM1_STAGE(A2, B2, tt + 2); WAITV(8); BAR(); MM1_COMP(A0, B0); BAR();
        MM1_STAGE(A0, B0, tt + 3); WAITV(8); BAR(); MM1_COMP(A1, B1); BAR();
        MM1_STAGE(A1, B1, tt + 4); WAITV(8); BAR(); MM1_COMP(A2, B2); BAR();
    }
    // peel: tiles 21 (stage 23), 22, 23
    MM1_STAGE(A2, B2, 23); WAITV(8); BAR(); MM1_COMP(A0, B0); BAR();
    WAITV(4); BAR(); MM1_COMP(A1, B1); BAR();
    WAITV(0); BAR(); MM1_COMP(A2, B2);

    // epilogue (swapped-operand layout): value(lane,reg r) =
    //   h[token = row0+wy*64+i*16+m_lane][col = col0+wx*64+j*16+quad*4+r]
    const int hbase = basep[e];
    #pragma unroll
    for (int i = 0; i < 4; i++) {
        int gr = row0 + wy * 64 + i * 16 + m_lane;      // token row
        if (gr < cnt) {
            _Float16* hrow = h + (size_t)(hbase + gr) * FDIM;
            #pragma unroll
            for (int j = 0; j < 4; j++) {
                int c = col0 + wx * 64 + j * 16 + quad * 4;
                float4 b4 = *(const float4*)&bias1[e * FDIM + c];
                f16x4 o;
                o[0] = (_Float16)gelu_exact(acc[i][j][0] + b4.x);
                o[1] = (_Float16)gelu_exact(acc[i][j][1] + b4.y);
                o[2] = (_Float16)gelu_exact(acc[i][j][2] + b4.z);
                o[3] = (_Float16)gelu_exact(acc[i][j][3] + b4.w);
                *(f16x4*)&hrow[c] = o;
            }
        }
    }
#undef MM1_STAGE
#undef MM1_COMP
}

// ---------------- GEMM2: out += gate_w * (h @ w2[e] + b2[e]) ----------------
// 64x128 tile (768 live blocks, 3/CU), BK=32, NT=96. Same 3-buffer
// counted-vmcnt pipeline; 3 loads/tile -> steady wait vmcnt(6), peel 6/3/0.
// Swapped MFMA operands -> 4 consecutive out columns per fragment.
__global__ __launch_bounds__(256) void mm2_kernel(const _Float16* __restrict__ h,
                                                  const _Float16* __restrict__ w2t,
                                                  const float* __restrict__ bias2,
                                                  const int* __restrict__ tok_list,
                                                  const float* __restrict__ wt_list,
                                                  const int* __restrict__ count,
                                                  const int* __restrict__ basep,
                                                  float* __restrict__ out) {
    const int e    = blockIdx.y;
    const int cnt  = count[e];
    const int row0 = blockIdx.z * 64;
    if (row0 >= cnt) return;
    const int col0 = blockIdx.x * 128;
    const int t    = threadIdx.x;
    const int lane = t & 63;
    const int wv   = t >> 6;            // wave -> 32-col group
    const int m_lane = lane & 15, quad = lane >> 4;

    __shared__ __align__(16) _Float16 A0[64][32],  A1[64][32],  A2[64][32];
    __shared__ __align__(16) _Float16 B0[128][32], B1[128][32], B2[128][32];

    const int srow    = t >> 2;                         // 0..63
    const int kin     = (t & 3) * 8;
    const int kin_src = ((t & 3) ^ ((srow >> 1) & 3)) * 8;

    const int hbase = basep[e];
    int ia = row0 + srow; if (ia > cnt - 1) ia = cnt - 1;
    const _Float16* pa  = h + (size_t)(hbase + ia) * FDIM + kin_src;
    const _Float16* pb0 = w2t + (size_t)e * DIM * FDIM + (size_t)(col0 + srow) * FDIM + kin_src;
    const _Float16* pb1 = pb0 + (size_t)64 * FDIM;

    f32x4 acc[4][2];
    #pragma unroll
    for (int i = 0; i < 4; i++)
        #pragma unroll
        for (int j = 0; j < 2; j++)
            acc[i][j] = (f32x4){0.f, 0.f, 0.f, 0.f};

    const int rc8 = (quad ^ ((m_lane >> 1) & 3)) * 8;

#define MM2_STAGE(Ad, Bd, kt) do { const int kk_ = (kt) * 32;          \
    gload_lds16(pa  + kk_, &Ad[srow][kin]);                             \
    gload_lds16(pb0 + kk_, &Bd[srow][kin]);                             \
    gload_lds16(pb1 + kk_, &Bd[64 + srow][kin]); } while (0)

#define MM2_COMP(Ac, Bc) do { f16x8 af_[4], bf_[2];                                         \
    _Pragma("unroll") for (int i_ = 0; i_ < 4; i_++)                                        \
        af_[i_] = *(const f16x8*)&Ac[i_ * 16 + m_lane][rc8];                                \
    _Pragma("unroll") for (int j_ = 0; j_ < 2; j_++)                                        \
        bf_[j_] = *(const f16x8*)&Bc[wv * 32 + j_ * 16 + m_lane][rc8];                      \
    _Pragma("unroll") for (int i_ = 0; i_ < 4; i_++)                                        \
        _Pragma("unroll") for (int j_ = 0; j_ < 2; j_++)                                    \
            acc[i_][j_] = __builtin_amdgcn_mfma_f32_16x16x32_f16(bf_[j_], af_[i_], acc[i_][j_], 0, 0, 0); } while (0)

    WAITV(0);
    MM2_STAGE(A0, B0, 0);
    MM2_STAGE(A1, B1, 1);
    // main: 31 iters, tiles 0..92, stages through tile 94
    for (int tt = 0; tt < 93; tt += 3) {
        MM2_STAGE(A2, B2, tt + 2); WAITV(6); BAR(); MM2_COMP(A0, B0); BAR();
        MM2_STAGE(A0, B0, tt + 3); WAITV(6); BAR(); MM2_COMP(A1, B1); BAR();
        MM2_STAGE(A1, B1, tt + 4); WAITV(6); BAR(); MM2_COMP(A2, B2); BAR();
    }
    // peel: tiles 93 (stage 95), 94, 95
    MM2_STAGE(A2, B2, 95); WAITV(6); BAR(); MM2_COMP(A0, B0); BAR();
    WAITV(3); BAR(); MM2_COMP(A1, B1); BAR();
    WAITV(0); BAR(); MM2_COMP(A2, B2);

    // epilogue: value(lane, r) = out[token = row0+i*16+m_lane][col = col0+wv*32+j*16+quad*4+r]
    #pragma unroll
    for (int i = 0; i < 4; i++) {
        int gr = row0 + i * 16 + m_lane;
        if (gr < cnt) {
            int tok   = tok_list[e * N_TOK + gr];
            float wgt = wt_list[e * N_TOK + gr];
            float* orow = out + (size_t)tok * DIM;
            #pragma unroll
            for (int j = 0; j < 2; j++) {
                int c = col0 + wv * 32 + j * 16 + quad * 4;
                float4 b4 = *(const float4*)&bias2[e * DIM + c];
                atomicAdd(&orow[c + 0], wgt * (acc[i][j][0] + b4.x));
                atomicAdd(&orow[c + 1], wgt * (acc[i][j][1] + b4.y));
                atomicAdd(&orow[c + 2], wgt * (acc[i][j][2] + b4.z));
                atomicAdd(&orow[c + 3], wgt * (acc[i][j][3] + b4.w));
            }
        }
    }
#undef MM2_STAGE
#undef MM2_COMP
}

extern "C" void kernel_launch(void* const* d_in, const int* in_sizes, int n_in,
                              void* d_out, int out_size, void* d_ws, size_t ws_size,
                              hipStream_t stream) {
    const float* x  = (const float*)d_in[0];
    const float* gw = (const float*)d_in[1];
    const float* gb = (const float*)d_in[2];
    const float* w1 = (const float*)d_in[3];
    const float* b1 = (const float*)d_in[4];
    const float* w2 = (const float*)d_in[5];
    const float* b2 = (const float*)d_in[6];
    float* out = (float*)d_out;

    // workspace layout (all 16B-aligned); total ~132.4 MB
    char* ws = (char*)d_ws;
    _Float16* xh   = (_Float16*)ws;                                    // 4096*768
    _Float16* w1t  = xh  + (size_t)N_TOK * DIM;                        // [E][F][D]
    _Float16* w2t  = w1t + (size_t)NEXP * FDIM * DIM;                  // [E][D][F]
    _Float16* hbuf = w2t + (size_t)NEXP * DIM * FDIM;                  // [2N][F] compact slots
    int*   tok_list = (int*)(hbuf + (size_t)2 * N_TOK * FDIM);         // [E][N]
    float* wt_list  = (float*)(tok_list + NEXP * N_TOK);               // [E][N]
    int*   count    = (int*)(wt_list + NEXP * N_TOK);                  // [E]
    int*   basep    = count + 8;                                       // [E]

    hipMemsetAsync(count, 0, 64, stream);                 // count + base
    hipMemsetAsync(out, 0, (size_t)out_size * sizeof(float), stream);

    cast_x_kernel<<<dim3(N_TOK * DIM / 4 / 256), 256, 0, stream>>>(x, xh);
    // w1: [E][768][3072] -> w1t [E][3072][768]; w2: [E][3072][768] -> w2t [E][768][3072]
    transpose_cast2_kernel<<<dim3(576, 16), 256, 0, stream>>>(w1, w2, w1t, w2t);
    gate_kernel<<<dim3(N_TOK / 4), 256, 0, stream>>>(x, gw, gb, tok_list, wt_list, count);
    scan_kernel<<<1, 64, 0, stream>>>(count, basep);
    // grid: (cols, experts, rowblocks) -> live blocks are a dense prefix
    mm1_kernel<<<dim3(FDIM / 128, NEXP, N_TOK / 128), 256, 0, stream>>>(
        xh, w1t, b1, tok_list, count, basep, hbuf);
    mm2_kernel<<<dim3(DIM / 128, NEXP, N_TOK / 64), 256, 0, stream>>>(
        hbuf, w2t, b2, tok_list, wt_list, count, basep, out);
}